// Round 1
// baseline (553.856 us; speedup 1.0000x reference)
//
#include <hip/hip_runtime.h>
#include <math.h>

#define Bn 32
#define Cn 256
#define Pn 1024                       // H*W tokens per batch
#define Tn (Bn * Pn * Cn)             // 8,388,608 elems per [b,p,c] tensor

typedef __bf16 bf16x8 __attribute__((ext_vector_type(8)));
typedef float  f32x4  __attribute__((ext_vector_type(4)));
typedef unsigned short u16;
typedef u16 u16x8 __attribute__((ext_vector_type(8)));

// ws layout in u16 units (total ~129 MiB):
#define XT1o ((size_t)0)              // xt of x1: [b][p][c] bf16
#define XT2o ((size_t)1 * Tn)         // xt of x2
#define Q1o  ((size_t)2 * Tn)         // q1 bf16 [b][p][c], pre-scaled 1/16
#define Ko   ((size_t)3 * Tn)         // k  bf16 [b][p][c]
#define VTo  ((size_t)4 * Tn)         // vt bf16 [b][c][p]
#define Q2o  ((size_t)5 * Tn)         // q2 bf16 [b][p][c], pre-scaled 1/16
#define H1o  ((size_t)6 * Tn)         // h1 bf16 [b][p][c]
#define H12o ((size_t)7 * Tn)         // h12 bf16 [b][p][c]
#define WBo  ((size_t)8 * Tn)         // 6 weight mats bf16 [o][c]: q1,k,v,q2,ps,pc

__device__ __forceinline__ u16 f2b(float f) {
    union { float f; unsigned u; } c; c.f = f;
    return (u16)((c.u + 0x7FFFu + ((c.u >> 16) & 1u)) >> 16);
}

// ---------------------------------------------------------------------------
// cvt: x1,x2 [b][c][p] fp32 -> xt [b][p][c] bf16 ; weights fp32 -> bf16.
// grid (16, 4, 70); block 256.
// ---------------------------------------------------------------------------
__global__ __launch_bounds__(256) void cvt_kernel(
    const float* __restrict__ x1, const float* __restrict__ x2,
    const float* __restrict__ wq1, const float* __restrict__ wk,
    const float* __restrict__ wv,  const float* __restrict__ wq2,
    const float* __restrict__ wps, const float* __restrict__ wpc,
    u16* __restrict__ ws16)
{
    const int z = blockIdx.z;
    const int tid = threadIdx.x;
    if (z >= 64) {
        const int widx = z - 64;
        const float* w = widx == 0 ? wq1 : widx == 1 ? wk : widx == 2 ? wv
                       : widx == 3 ? wq2 : widx == 4 ? wps : wpc;
        const int linear = blockIdx.x + 16 * blockIdx.y;   // 0..63
        const int e = linear * 1024 + tid * 4;
        float4 v = *(const float4*)&w[e];
        ushort4 o = make_ushort4(f2b(v.x), f2b(v.y), f2b(v.z), f2b(v.w));
        *(ushort4*)&ws16[WBo + (size_t)widx * 65536 + e] = o;
        return;
    }
    const int which = z >> 5, b = z & 31;
    const float* x = which ? x2 : x1;
    u16* xt = ws16 + (which ? XT2o : XT1o);
    const int p0 = blockIdx.x * 64, c0 = blockIdx.y * 64;
    __shared__ __align__(16) u16 T[64][80];
    #pragma unroll
    for (int i = 0; i < 4; i++) {
        int e = tid + i * 256;
        int c = e >> 4, p4 = e & 15;
        float4 v = *(const float4*)&x[((size_t)(b * Cn + c0 + c)) * Pn + p0 + p4 * 4];
        T[p4 * 4 + 0][c] = f2b(v.x);
        T[p4 * 4 + 1][c] = f2b(v.y);
        T[p4 * 4 + 2][c] = f2b(v.z);
        T[p4 * 4 + 3][c] = f2b(v.w);
    }
    __syncthreads();
    #pragma unroll
    for (int i = 0; i < 2; i++) {
        int e = tid + i * 256;
        int p = e >> 3, c8 = e & 7;
        u16x8 vv = *(const u16x8*)&T[p][c8 * 8];
        *(u16x8*)&xt[((size_t)(b * Pn + p0 + p)) * Cn + c0 + c8 * 8] = vv;
    }
}

// ---------------------------------------------------------------------------
// Shared 128x128x256 MFMA GEMM core, register-prefetch pipeline (R5 lesson):
// chunk k+1's global loads are issued right after chunk k's tiles become
// visible, so VMEM latency hides behind chunk k's frag reads + 32 MFMAs.
// Staging/swizzle layout bit-identical to the R3-verified core.
// ---------------------------------------------------------------------------
__device__ __forceinline__ void gemm_core(
    const u16* __restrict__ Ab, const u16* __restrict__ Bb,
    u16* __restrict__ As, u16* __restrict__ Bs, f32x4 acc[16], int tid)
{
    const int wv = tid >> 6, lane = tid & 63;
    const int ln = lane & 15, quad = lane >> 4;
    const int wr = wv >> 1, wc = wv & 1;
    const int srow = tid >> 3, sch = tid & 7;    // staging role
    const int pos = sch ^ (srow & 7);            // (srow+32i)&7 == srow&7

    u16x8 apre[4], bpre[4];
    #pragma unroll
    for (int i = 0; i < 4; i++) {
        int r = srow + 32 * i;
        apre[i] = *(const u16x8*)&Ab[(size_t)r * 256 + sch * 8];
        bpre[i] = *(const u16x8*)&Bb[(size_t)r * 256 + sch * 8];
    }

    for (int k0 = 0; k0 < 256; k0 += 64) {
        __syncthreads();
        #pragma unroll
        for (int i = 0; i < 4; i++) {
            int r = srow + 32 * i;
            *(u16x8*)&As[r * 64 + pos * 8] = apre[i];
            *(u16x8*)&Bs[r * 64 + pos * 8] = bpre[i];
        }
        __syncthreads();
        if (k0 < 192) {
            #pragma unroll
            for (int i = 0; i < 4; i++) {
                int r = srow + 32 * i;
                apre[i] = *(const u16x8*)&Ab[(size_t)r * 256 + (k0 + 64) + sch * 8];
                bpre[i] = *(const u16x8*)&Bb[(size_t)r * 256 + (k0 + 64) + sch * 8];
            }
        }
        bf16x8 af[4][2], bf[4][2];
        #pragma unroll
        for (int i = 0; i < 4; i++) {
            int row = wr * 64 + i * 16 + ln;
            #pragma unroll
            for (int kc = 0; kc < 2; kc++) {
                int p = (kc * 4 + quad) ^ (row & 7);
                af[i][kc] = *(const bf16x8*)&As[row * 64 + p * 8];
            }
        }
        #pragma unroll
        for (int j = 0; j < 4; j++) {
            int row = wc * 64 + j * 16 + ln;
            #pragma unroll
            for (int kc = 0; kc < 2; kc++) {
                int p = (kc * 4 + quad) ^ (row & 7);
                bf[j][kc] = *(const bf16x8*)&Bs[row * 64 + p * 8];
            }
        }
        #pragma unroll
        for (int kc = 0; kc < 2; kc++)
            #pragma unroll
            for (int i = 0; i < 4; i++)
                #pragma unroll
                for (int j = 0; j < 4; j++)
                    acc[i * 4 + j] = __builtin_amdgcn_mfma_f32_16x16x32_bf16(
                        af[i][kc], bf[j][kc], acc[i * 4 + j], 0, 0, 0);
    }
}

// ---------------------------------------------------------------------------
// proj: q1/k/q2 (mat 0,1,2): [32768 x 256] = xt . W^T ; V (mat 3): vt = W . xt^T
// grid (512, 4); block 256
// ---------------------------------------------------------------------------
__global__ __launch_bounds__(256) void proj_kernel(
    u16* __restrict__ ws16,
    const float* __restrict__ bq1, const float* __restrict__ bk,
    const float* __restrict__ bq2, const float* __restrict__ bv)
{
    __shared__ __align__(16) u16 As[128 * 64];
    __shared__ __align__(16) u16 Bs[128 * 64];
    const int tid = threadIdx.x;
    const int mat = blockIdx.y;
    const int wv = tid >> 6, lane = tid & 63;
    const int ln = lane & 15, quad = lane >> 4;
    const int wr = wv >> 1, wc = wv & 1;

    f32x4 acc[16];
    #pragma unroll
    for (int t = 0; t < 16; t++) acc[t] = (f32x4){0.f, 0.f, 0.f, 0.f};

    if (mat < 3) {
        const int m_tile = blockIdx.x >> 1, n_tile = blockIdx.x & 1;
        const size_t xtoff = (mat == 2) ? XT2o : XT1o;
        const int widx = (mat == 0) ? 0 : (mat == 1) ? 1 : 3;
        const float* bias = (mat == 0) ? bq1 : (mat == 1) ? bk : bq2;
        const float scale = (mat == 1) ? 1.0f : 0.0625f;
        u16* out = ws16 + ((mat == 0) ? Q1o : (mat == 1) ? Ko : Q2o);

        const u16* Ab = ws16 + xtoff + (size_t)m_tile * 128 * 256;
        const u16* Bb = ws16 + WBo + (size_t)widx * 65536 + (size_t)n_tile * 128 * 256;
        gemm_core(Ab, Bb, As, Bs, acc, tid);

        const int m0 = m_tile * 128;
        #pragma unroll
        for (int j = 0; j < 4; j++) {
            const int ncol = n_tile * 128 + wc * 64 + j * 16 + ln;
            const float bj = bias[ncol];
            #pragma unroll
            for (int i = 0; i < 4; i++) {
                const int mr = m0 + wr * 64 + i * 16 + quad * 4;
                #pragma unroll
                for (int r = 0; r < 4; r++)
                    out[(size_t)(mr + r) * 256 + ncol] =
                        f2b((acc[i * 4 + j][r] + bj) * scale);
            }
        }
    } else {
        const int b = blockIdx.x >> 4;
        const int o_tile = (blockIdx.x >> 3) & 1;
        const int p_tile = blockIdx.x & 7;
        const u16* Ab = ws16 + WBo + (size_t)2 * 65536 + (size_t)o_tile * 128 * 256;
        const u16* Bb = ws16 + XT1o + ((size_t)b * Pn + p_tile * 128) * 256;
        gemm_core(Ab, Bb, As, Bs, acc, tid);

        u16* vt = ws16 + VTo + (size_t)b * Cn * Pn;
        #pragma unroll
        for (int i = 0; i < 4; i++) {
            #pragma unroll
            for (int r = 0; r < 4; r++) {
                const int orow = o_tile * 128 + wr * 64 + i * 16 + quad * 4 + r;
                const float bo = bv[orow];
                #pragma unroll
                for (int j = 0; j < 4; j++) {
                    const int pcol = p_tile * 128 + wc * 64 + j * 16 + ln;
                    vt[(size_t)orow * Pn + pcol] = f2b(acc[i * 4 + j][r] + bo);
                }
            }
        }
    }
}

// ---------------------------------------------------------------------------
// attn v4: LDS-pipe offload. R6 counters showed all pipes <30% with ~58 LDS
// ops/wave-iter (~4.8K cyc/CU-iter) vs 620 cyc of MFMA/SIMD -> LDS-bound.
// Change: V fragments are read straight from global Vt [b][c][p] (the staged
// path was the identity: stored chunk gp=gvV^(cl&3), read chunk quad^(ln&3)
// at row cl -> global chunk quad). 2x4-frag register pipeline hides L2
// latency under QK. Vtlds (16KB + all 4-way-conflict reads) and vpre die.
// XCD-affinity swizzle groups 4 batches/XCD so K+V (4MB bf16) stay L2-local.
// s1v/s2v staging folded into the st loop to keep VGPR<=128 (+128 AGPR acc
// = 256 = 2 waves/SIMD; any more halves occupancy).
// block = 4 waves = 64 q-rows; 32 k-tokens per iter. grid (16, 32).
// ---------------------------------------------------------------------------
__global__ __launch_bounds__(256, 2) void attn_kernel(u16* __restrict__ ws16)
{
    const u16* Q1 = ws16 + Q1o;
    const u16* Kg = ws16 + Ko;
    const u16* Vt = ws16 + VTo;
    const u16* Q2 = ws16 + Q2o;

    __shared__ __align__(16) u16 Klds[32 * 256];    // [tok][c], chunk swizzle ^ (tok&7)
    __shared__ __align__(16) u16 Plds[4 * 2 * 16 * 40];  // per-wave P1/P12, pad 40

    // XCD-affinity remap: linear dispatch id round-robins the 8 XCDs, so
    // give XCD x batches 4x..4x+3 (K+V = 4MB bf16 = one XCD's L2).
    // fid = (b>>2) + 8*((b&3) + 4*q)  -- bijective over 512 blocks.
    const int fid = blockIdx.x + (blockIdx.y << 4);
    const int b   = ((fid & 7) << 2) | ((fid >> 3) & 3);
    const int q0  = (fid >> 5) << 6;

    const int tid  = threadIdx.x;
    const int wid  = tid >> 6;
    const int lane = tid & 63;
    const int ln   = lane & 15;
    const int quad = lane >> 4;
    u16* Pw = Plds + wid * (2 * 16 * 40);

    const size_t qrow = (size_t)(b * Pn + q0 + wid * 16 + ln) * Cn;
    bf16x8 qa1[8], qa2[8];
    #pragma unroll
    for (int ch = 0; ch < 8; ch++) {
        qa1[ch] = *(const bf16x8*)&Q1[qrow + ch * 32 + quad * 8];
        qa2[ch] = *(const bf16x8*)&Q2[qrow + ch * 32 + quad * 8];
    }

    f32x4 acc1[16], acc12[16];
    #pragma unroll
    for (int t = 0; t < 16; t++) {
        acc1[t] = (f32x4){0.f, 0.f, 0.f, 0.f};
        acc12[t] = (f32x4){0.f, 0.f, 0.f, 0.f};
    }
    float lp1[4] = {}, lp12[4] = {};

    const int tokK = tid >> 3, giK = tid & 7;
    u16x8 kpre[4];
    {
        const size_t growK = (size_t)(b * Pn + tokK) * Cn;
        #pragma unroll
        for (int i = 0; i < 4; i++)
            kpre[i] = *(const u16x8*)&Kg[growK + (size_t)(8 * i + (giK ^ (tokK & 7))) * 8];
    }

    // per-lane V base: c-row = t*16 + ln, token chunk = quad (16B, aligned)
    const size_t vbase = ((size_t)b * Cn + ln) * Pn + quad * 8;

    for (int kt = 0; kt < 32; kt++) {
        const int k0 = kt * 32;
        __syncthreads();   // (A) all waves done reading Klds of prev iter

        #pragma unroll
        for (int i = 0; i < 4; i++)
            *(u16x8*)&Klds[tokK * 256 + (8 * i + giK) * 8] = kpre[i];
        __syncthreads();   // (B) tile visible

        if (kt < 31) {
            const size_t growK = (size_t)(b * Pn + k0 + 32 + tokK) * Cn;
            #pragma unroll
            for (int i = 0; i < 4; i++)
                kpre[i] = *(const u16x8*)&Kg[growK + (size_t)(8 * i + (giK ^ (tokK & 7))) * 8];
        }

        // V fragments, first half (t = 0..3): issued before QK so the
        // ~400 cyc of QK MFMAs cover L1/L2 latency.
        bf16x8 vb0[4], vb1[4];
        #pragma unroll
        for (int i = 0; i < 4; i++)
            vb0[i] = *(const bf16x8*)&Vt[vbase + (size_t)(i * 16) * Pn + k0];

        #pragma unroll
        for (int st = 0; st < 2; st++) {
            f32x4 s1 = (f32x4){0.f, 0.f, 0.f, 0.f};
            f32x4 s2 = (f32x4){0.f, 0.f, 0.f, 0.f};
            __builtin_amdgcn_s_setprio(1);
            #pragma unroll
            for (int ch = 0; ch < 8; ch++) {
                bf16x8 kb = *(const bf16x8*)
                    &Klds[(st * 16 + ln) * 256 + (((ch * 4 + quad) ^ (ln & 7))) * 8];
                s1 = __builtin_amdgcn_mfma_f32_16x16x32_bf16(qa1[ch], kb, s1, 0, 0, 0);
                s2 = __builtin_amdgcn_mfma_f32_16x16x32_bf16(qa2[ch], kb, s2, 0, 0, 0);
            }
            __builtin_amdgcn_s_setprio(0);
            if (st == 0) {   // second-half V loads, covered by exp + st=1
                #pragma unroll
                for (int i = 0; i < 4; i++)
                    vb1[i] = *(const bf16x8*)&Vt[vbase + (size_t)((i + 4) * 16) * Pn + k0];
            }
            #pragma unroll
            for (int r = 0; r < 4; r++) {
                float p1 = __expf(s1[r]);
                float p12 = p1 * __expf(s2[r]);
                lp1[r] += p1;
                lp12[r] += p12;
                const int row = quad * 4 + r, col = st * 16 + ln;
                Pw[row * 40 + col]           = f2b(p1);
                Pw[16 * 40 + row * 40 + col] = f2b(p12);
            }
        }

        bf16x8 pa1 = *(const bf16x8*)&Pw[ln * 40 + quad * 8];
        bf16x8 pa2 = *(const bf16x8*)&Pw[16 * 40 + ln * 40 + quad * 8];

        __builtin_amdgcn_s_setprio(1);
        #pragma unroll
        for (int t = 0; t < 4; t++) {
            acc1[t]  = __builtin_amdgcn_mfma_f32_16x16x32_bf16(pa1, vb0[t], acc1[t], 0, 0, 0);
            acc12[t] = __builtin_amdgcn_mfma_f32_16x16x32_bf16(pa2, vb0[t], acc12[t], 0, 0, 0);
        }
        __builtin_amdgcn_s_setprio(0);
        #pragma unroll
        for (int i = 0; i < 4; i++)
            vb0[i] = *(const bf16x8*)&Vt[vbase + (size_t)((i + 8) * 16) * Pn + k0];
        __builtin_amdgcn_s_setprio(1);
        #pragma unroll
        for (int t = 4; t < 8; t++) {
            acc1[t]  = __builtin_amdgcn_mfma_f32_16x16x32_bf16(pa1, vb1[t - 4], acc1[t], 0, 0, 0);
            acc12[t] = __builtin_amdgcn_mfma_f32_16x16x32_bf16(pa2, vb1[t - 4], acc12[t], 0, 0, 0);
        }
        __builtin_amdgcn_s_setprio(0);
        #pragma unroll
        for (int i = 0; i < 4; i++)
            vb1[i] = *(const bf16x8*)&Vt[vbase + (size_t)((i + 12) * 16) * Pn + k0];
        __builtin_amdgcn_s_setprio(1);
        #pragma unroll
        for (int t = 8; t < 12; t++) {
            acc1[t]  = __builtin_amdgcn_mfma_f32_16x16x32_bf16(pa1, vb0[t - 8], acc1[t], 0, 0, 0);
            acc12[t] = __builtin_amdgcn_mfma_f32_16x16x32_bf16(pa2, vb0[t - 8], acc12[t], 0, 0, 0);
        }
        #pragma unroll
        for (int t = 12; t < 16; t++) {
            acc1[t]  = __builtin_amdgcn_mfma_f32_16x16x32_bf16(pa1, vb1[t - 12], acc1[t], 0, 0, 0);
            acc12[t] = __builtin_amdgcn_mfma_f32_16x16x32_bf16(pa2, vb1[t - 12], acc12[t], 0, 0, 0);
        }
        __builtin_amdgcn_s_setprio(0);
    }

    u16* H1 = ws16 + H1o;
    u16* H12 = ws16 + H12o;
    #pragma unroll
    for (int r = 0; r < 4; r++) {
        float l1 = lp1[r], l2 = lp12[r];
        l1 += __shfl_xor(l1, 1); l2 += __shfl_xor(l2, 1);
        l1 += __shfl_xor(l1, 2); l2 += __shfl_xor(l2, 2);
        l1 += __shfl_xor(l1, 4); l2 += __shfl_xor(l2, 4);
        l1 += __shfl_xor(l1, 8); l2 += __shfl_xor(l2, 8);
        float i1 = 1.f / l1, i2 = 1.f / l2;
        size_t rowb = (size_t)(b * Pn + q0 + wid * 16 + quad * 4 + r) * Cn;
        #pragma unroll
        for (int t = 0; t < 16; t++) {
            H1[rowb + t * 16 + ln]  = f2b(acc1[t][r] * i1);
            H12[rowb + t * 16 + ln] = f2b(acc12[t][r] * i2);
        }
    }
}

// ---------------------------------------------------------------------------
// outproj: out[mat][b][o][p] = x1[b][o][p] + bias[o] + sum_c h[b][p][c]*w[o][c]
// grid (16, 64); block 256
// ---------------------------------------------------------------------------
__global__ __launch_bounds__(256) void outproj_kernel(
    const float* __restrict__ x1,
    const float* __restrict__ bps, const float* __restrict__ bpc,
    const u16* __restrict__ ws16, float* __restrict__ outp)
{
    __shared__ __align__(16) u16 As[128 * 64];
    __shared__ __align__(16) u16 Bs[128 * 64];
    const int tid = threadIdx.x;
    const int o_tile = blockIdx.x >> 3, p_tile = blockIdx.x & 7;
    const int mat = blockIdx.y >> 5, b = blockIdx.y & 31;
    const int wv = tid >> 6, lane = tid & 63;
    const int ln = lane & 15, quad = lane >> 4;
    const int wr = wv >> 1, wc = wv & 1;

    f32x4 acc[16];
    #pragma unroll
    for (int t = 0; t < 16; t++) acc[t] = (f32x4){0.f, 0.f, 0.f, 0.f};

    const u16* Ab = ws16 + WBo + (size_t)(4 + mat) * 65536 + (size_t)o_tile * 128 * 256;
    const u16* Bb = ws16 + (mat ? H12o : H1o) + ((size_t)b * Pn + p_tile * 128) * 256;
    gemm_core(Ab, Bb, As, Bs, acc, tid);

    const float* bias = mat ? bpc : bps;
    float* out = outp + (size_t)mat * Tn;
    #pragma unroll
    for (int i = 0; i < 4; i++) {
        #pragma unroll
        for (int r = 0; r < 4; r++) {
            const int orow = o_tile * 128 + wr * 64 + i * 16 + quad * 4 + r;
            const float bo = bias[orow];
            #pragma unroll
            for (int j = 0; j < 4; j++) {
                const int pcol = p_tile * 128 + wc * 64 + j * 16 + ln;
                const size_t idx = ((size_t)b * Cn + orow) * Pn + pcol;
                out[idx] = x1[idx] + bo + acc[i * 4 + j][r];
            }
        }
    }
}

// ---------------------------------------------------------------------------
extern "C" void kernel_launch(void* const* d_in, const int* in_sizes, int n_in,
                              void* d_out, int out_size, void* d_ws, size_t ws_size,
                              hipStream_t stream)
{
    const float* x1  = (const float*)d_in[0];
    const float* x2  = (const float*)d_in[1];
    const float* wq1 = (const float*)d_in[2];
    const float* bq1 = (const float*)d_in[3];
    const float* wk  = (const float*)d_in[4];
    const float* bk  = (const float*)d_in[5];
    const float* wv  = (const float*)d_in[6];
    const float* bv  = (const float*)d_in[7];
    const float* wq2 = (const float*)d_in[8];
    const float* bq2 = (const float*)d_in[9];
    const float* wps = (const float*)d_in[10];
    const float* bps = (const float*)d_in[11];
    const float* wpc = (const float*)d_in[12];
    const float* bpc = (const float*)d_in[13];
    float* out = (float*)d_out;
    u16* ws16 = (u16*)d_ws;

    cvt_kernel<<<dim3(16, 4, 70), 256, 0, stream>>>(
        x1, x2, wq1, wk, wv, wq2, wps, wpc, ws16);
    proj_kernel<<<dim3(512, 4), 256, 0, stream>>>(ws16, bq1, bk, bq2, bv);
    attn_kernel<<<dim3(Pn / 64, Bn), 256, 0, stream>>>(ws16);
    outproj_kernel<<<dim3(16, 64), 256, 0, stream>>>(x1, bps, bpc, ws16, out);
}

// Round 2
// 357.850 us; speedup vs baseline: 1.5477x; 1.5477x over previous
//
#include <hip/hip_runtime.h>
#include <math.h>

#define Bn 32
#define Cn 256
#define Pn 1024                       // H*W tokens per batch
#define Tn (Bn * Pn * Cn)             // 8,388,608 elems per [b,p,c] tensor

typedef __bf16 bf16x8 __attribute__((ext_vector_type(8)));
typedef float  f32x4  __attribute__((ext_vector_type(4)));
typedef unsigned short u16;
typedef unsigned int u32;
typedef u16 u16x8 __attribute__((ext_vector_type(8)));

// ws layout in u16 units (total ~129 MiB):
#define XT1o ((size_t)0)              // xt of x1: [b][p][c] bf16
#define XT2o ((size_t)1 * Tn)         // xt of x2
#define Q1o  ((size_t)2 * Tn)         // q1 bf16 [b][p][c], pre-scaled 1/16
#define Ko   ((size_t)3 * Tn)         // k  bf16 [b][p][c]
#define VTo  ((size_t)4 * Tn)         // vt bf16 [b][c][p]
#define Q2o  ((size_t)5 * Tn)         // q2 bf16 [b][p][c], pre-scaled 1/16
#define H1o  ((size_t)6 * Tn)         // h1 bf16 [b][p][c]
#define H12o ((size_t)7 * Tn)         // h12 bf16 [b][p][c]
#define WBo  ((size_t)8 * Tn)         // 6 weight mats bf16 [o][c]: q1,k,v,q2,ps,pc

__device__ __forceinline__ u16 f2b(float f) {
    union { float f; unsigned u; } c; c.f = f;
    return (u16)((c.u + 0x7FFFu + ((c.u >> 16) & 1u)) >> 16);
}

// pack two f32 -> one u32 of 2 bf16 (RNE, same as f2b)
__device__ __forceinline__ u32 cvt_pk_bf16(float lo, float hi) {
    u32 r;
    asm("v_cvt_pk_bf16_f32 %0, %1, %2" : "=v"(r) : "v"(lo), "v"(hi));
    return r;
}
// exchange lanes 32-63 of x with lanes 0-31 of y
__device__ __forceinline__ void pl32swap(u32& x, u32& y) {
    asm("v_permlane32_swap_b32 %0, %1" : "+v"(x), "+v"(y));
}
// exchange lanes 16-31 of x with 0-15 of y, and 48-63 of x with 32-47 of y
__device__ __forceinline__ void pl16swap(u32& x, u32& y) {
    asm("v_permlane16_swap_b32 %0, %1" : "+v"(x), "+v"(y));
}
__device__ __forceinline__ bf16x8 pkfrag(u32 a, u32 b, u32 c, u32 d) {
    union { u32 u[4]; bf16x8 v; } x;
    x.u[0] = a; x.u[1] = b; x.u[2] = c; x.u[3] = d;
    return x.v;
}

// ---------------------------------------------------------------------------
// cvt: x1,x2 [b][c][p] fp32 -> xt [b][p][c] bf16 ; weights fp32 -> bf16.
// grid (16, 4, 70); block 256.
// ---------------------------------------------------------------------------
__global__ __launch_bounds__(256) void cvt_kernel(
    const float* __restrict__ x1, const float* __restrict__ x2,
    const float* __restrict__ wq1, const float* __restrict__ wk,
    const float* __restrict__ wv,  const float* __restrict__ wq2,
    const float* __restrict__ wps, const float* __restrict__ wpc,
    u16* __restrict__ ws16)
{
    const int z = blockIdx.z;
    const int tid = threadIdx.x;
    if (z >= 64) {
        const int widx = z - 64;
        const float* w = widx == 0 ? wq1 : widx == 1 ? wk : widx == 2 ? wv
                       : widx == 3 ? wq2 : widx == 4 ? wps : wpc;
        const int linear = blockIdx.x + 16 * blockIdx.y;   // 0..63
        const int e = linear * 1024 + tid * 4;
        float4 v = *(const float4*)&w[e];
        ushort4 o = make_ushort4(f2b(v.x), f2b(v.y), f2b(v.z), f2b(v.w));
        *(ushort4*)&ws16[WBo + (size_t)widx * 65536 + e] = o;
        return;
    }
    const int which = z >> 5, b = z & 31;
    const float* x = which ? x2 : x1;
    u16* xt = ws16 + (which ? XT2o : XT1o);
    const int p0 = blockIdx.x * 64, c0 = blockIdx.y * 64;
    __shared__ __align__(16) u16 T[64][80];
    #pragma unroll
    for (int i = 0; i < 4; i++) {
        int e = tid + i * 256;
        int c = e >> 4, p4 = e & 15;
        float4 v = *(const float4*)&x[((size_t)(b * Cn + c0 + c)) * Pn + p0 + p4 * 4];
        T[p4 * 4 + 0][c] = f2b(v.x);
        T[p4 * 4 + 1][c] = f2b(v.y);
        T[p4 * 4 + 2][c] = f2b(v.z);
        T[p4 * 4 + 3][c] = f2b(v.w);
    }
    __syncthreads();
    #pragma unroll
    for (int i = 0; i < 2; i++) {
        int e = tid + i * 256;
        int p = e >> 3, c8 = e & 7;
        u16x8 vv = *(const u16x8*)&T[p][c8 * 8];
        *(u16x8*)&xt[((size_t)(b * Pn + p0 + p)) * Cn + c0 + c8 * 8] = vv;
    }
}

// ---------------------------------------------------------------------------
// Shared 128x128x256 MFMA GEMM core, register-prefetch pipeline (R5 lesson).
// ---------------------------------------------------------------------------
__device__ __forceinline__ void gemm_core(
    const u16* __restrict__ Ab, const u16* __restrict__ Bb,
    u16* __restrict__ As, u16* __restrict__ Bs, f32x4 acc[16], int tid)
{
    const int wv = tid >> 6, lane = tid & 63;
    const int ln = lane & 15, quad = lane >> 4;
    const int wr = wv >> 1, wc = wv & 1;
    const int srow = tid >> 3, sch = tid & 7;    // staging role
    const int pos = sch ^ (srow & 7);            // (srow+32i)&7 == srow&7

    u16x8 apre[4], bpre[4];
    #pragma unroll
    for (int i = 0; i < 4; i++) {
        int r = srow + 32 * i;
        apre[i] = *(const u16x8*)&Ab[(size_t)r * 256 + sch * 8];
        bpre[i] = *(const u16x8*)&Bb[(size_t)r * 256 + sch * 8];
    }

    for (int k0 = 0; k0 < 256; k0 += 64) {
        __syncthreads();
        #pragma unroll
        for (int i = 0; i < 4; i++) {
            int r = srow + 32 * i;
            *(u16x8*)&As[r * 64 + pos * 8] = apre[i];
            *(u16x8*)&Bs[r * 64 + pos * 8] = bpre[i];
        }
        __syncthreads();
        if (k0 < 192) {
            #pragma unroll
            for (int i = 0; i < 4; i++) {
                int r = srow + 32 * i;
                apre[i] = *(const u16x8*)&Ab[(size_t)r * 256 + (k0 + 64) + sch * 8];
                bpre[i] = *(const u16x8*)&Bb[(size_t)r * 256 + (k0 + 64) + sch * 8];
            }
        }
        bf16x8 af[4][2], bf[4][2];
        #pragma unroll
        for (int i = 0; i < 4; i++) {
            int row = wr * 64 + i * 16 + ln;
            #pragma unroll
            for (int kc = 0; kc < 2; kc++) {
                int p = (kc * 4 + quad) ^ (row & 7);
                af[i][kc] = *(const bf16x8*)&As[row * 64 + p * 8];
            }
        }
        #pragma unroll
        for (int j = 0; j < 4; j++) {
            int row = wc * 64 + j * 16 + ln;
            #pragma unroll
            for (int kc = 0; kc < 2; kc++) {
                int p = (kc * 4 + quad) ^ (row & 7);
                bf[j][kc] = *(const bf16x8*)&Bs[row * 64 + p * 8];
            }
        }
        #pragma unroll
        for (int kc = 0; kc < 2; kc++)
            #pragma unroll
            for (int i = 0; i < 4; i++)
                #pragma unroll
                for (int j = 0; j < 4; j++)
                    acc[i * 4 + j] = __builtin_amdgcn_mfma_f32_16x16x32_bf16(
                        af[i][kc], bf[j][kc], acc[i * 4 + j], 0, 0, 0);
    }
}

// ---------------------------------------------------------------------------
// proj: q1/k/q2 (mat 0,1,2): [32768 x 256] = xt . W^T ; V (mat 3): vt = W . xt^T
// grid (512, 4); block 256
// ---------------------------------------------------------------------------
__global__ __launch_bounds__(256) void proj_kernel(
    u16* __restrict__ ws16,
    const float* __restrict__ bq1, const float* __restrict__ bk,
    const float* __restrict__ bq2, const float* __restrict__ bv)
{
    __shared__ __align__(16) u16 As[128 * 64];
    __shared__ __align__(16) u16 Bs[128 * 64];
    const int tid = threadIdx.x;
    const int mat = blockIdx.y;
    const int wv = tid >> 6, lane = tid & 63;
    const int ln = lane & 15, quad = lane >> 4;
    const int wr = wv >> 1, wc = wv & 1;

    f32x4 acc[16];
    #pragma unroll
    for (int t = 0; t < 16; t++) acc[t] = (f32x4){0.f, 0.f, 0.f, 0.f};

    if (mat < 3) {
        const int m_tile = blockIdx.x >> 1, n_tile = blockIdx.x & 1;
        const size_t xtoff = (mat == 2) ? XT2o : XT1o;
        const int widx = (mat == 0) ? 0 : (mat == 1) ? 1 : 3;
        const float* bias = (mat == 0) ? bq1 : (mat == 1) ? bk : bq2;
        const float scale = (mat == 1) ? 1.0f : 0.0625f;
        u16* out = ws16 + ((mat == 0) ? Q1o : (mat == 1) ? Ko : Q2o);

        const u16* Ab = ws16 + xtoff + (size_t)m_tile * 128 * 256;
        const u16* Bb = ws16 + WBo + (size_t)widx * 65536 + (size_t)n_tile * 128 * 256;
        gemm_core(Ab, Bb, As, Bs, acc, tid);

        const int m0 = m_tile * 128;
        #pragma unroll
        for (int j = 0; j < 4; j++) {
            const int ncol = n_tile * 128 + wc * 64 + j * 16 + ln;
            const float bj = bias[ncol];
            #pragma unroll
            for (int i = 0; i < 4; i++) {
                const int mr = m0 + wr * 64 + i * 16 + quad * 4;
                #pragma unroll
                for (int r = 0; r < 4; r++)
                    out[(size_t)(mr + r) * 256 + ncol] =
                        f2b((acc[i * 4 + j][r] + bj) * scale);
            }
        }
    } else {
        const int b = blockIdx.x >> 4;
        const int o_tile = (blockIdx.x >> 3) & 1;
        const int p_tile = blockIdx.x & 7;
        const u16* Ab = ws16 + WBo + (size_t)2 * 65536 + (size_t)o_tile * 128 * 256;
        const u16* Bb = ws16 + XT1o + ((size_t)b * Pn + p_tile * 128) * 256;
        gemm_core(Ab, Bb, As, Bs, acc, tid);

        u16* vt = ws16 + VTo + (size_t)b * Cn * Pn;
        #pragma unroll
        for (int i = 0; i < 4; i++) {
            #pragma unroll
            for (int r = 0; r < 4; r++) {
                const int orow = o_tile * 128 + wr * 64 + i * 16 + quad * 4 + r;
                const float bo = bv[orow];
                #pragma unroll
                for (int j = 0; j < 4; j++) {
                    const int pcol = p_tile * 128 + wc * 64 + j * 16 + ln;
                    vt[(size_t)orow * Pn + pcol] = f2b(acc[i * 4 + j][r] + bo);
                }
            }
        }
    }
}

// ---------------------------------------------------------------------------
// attn v5: v3 structure (K AND V staged in LDS, register K/V prefetch,
// two barriers/iter) -- the v4 global-V experiment thrashed L2 and caused
// RMW write amplification on the 2B H stores (FETCH/WRITE +500MB each).
// New here: the P LDS round-trip (16 ds_write_u16 + 2 ds_read_b128/wave-iter,
// the source of ~all 8.9M bank-conflict cycles) is replaced by a pure-VALU
// in-register transpose:
//   - QK computed SWAPPED: S^T = mfma(K, Q) -> lane holds q = ln (lane-local),
//     k = st*16 + quad*4 + r.
//   - 8x v_cvt_pk_bf16_f32 + 4x v_permlane32_swap + 4x v_permlane16_swap
//     rearrange to the PV B-fragment (q = ln, k = quad*8..+8). Verified
//     element-wise for lanes (quad=1,ln=0) and (quad=2,ln=0).
//   - PV computed as O^T = mfma(V^T, P^T); V^T fragment read is bit-identical
//     to v3's. Epilogue: acc holds c = t*16+quad*4+r for q = ln -> r-contiguous
//     ushort4 stores (4x fewer store instrs); lp is one scalar/lane reduced
//     with shfl_xor(16/32).
// block = 4 waves = 64 q-rows; 32 k-tokens per iter. grid (16, 32).
// ---------------------------------------------------------------------------
__global__ __launch_bounds__(256, 2) void attn_kernel(u16* __restrict__ ws16)
{
    const u16* Q1 = ws16 + Q1o;
    const u16* Kg = ws16 + Ko;
    const u16* Vt = ws16 + VTo;
    const u16* Q2 = ws16 + Q2o;

    __shared__ __align__(16) u16 Klds[32 * 256];    // [tok][c], chunk swizzle ^ (tok&7)
    __shared__ __align__(16) u16 Vtlds[256 * 32];   // [c][tok], chunk swizzle ^ (c&3)

    const int b    = blockIdx.y;
    const int q0   = blockIdx.x * 64;
    const int tid  = threadIdx.x;
    const int wid  = tid >> 6;
    const int lane = tid & 63;
    const int ln   = lane & 15;
    const int quad = lane >> 4;

    const size_t qrow = (size_t)(b * Pn + q0 + wid * 16 + ln) * Cn;
    bf16x8 qa1[8], qa2[8];
    #pragma unroll
    for (int ch = 0; ch < 8; ch++) {
        qa1[ch] = *(const bf16x8*)&Q1[qrow + ch * 32 + quad * 8];
        qa2[ch] = *(const bf16x8*)&Q2[qrow + ch * 32 + quad * 8];
    }

    f32x4 acc1[16], acc12[16];
    #pragma unroll
    for (int t = 0; t < 16; t++) {
        acc1[t] = (f32x4){0.f, 0.f, 0.f, 0.f};
        acc12[t] = (f32x4){0.f, 0.f, 0.f, 0.f};
    }
    float lp1 = 0.f, lp12 = 0.f;

    const int tokK = tid >> 3, giK = tid & 7;
    const int cbV = tid >> 2, gvV = tid & 3;
    u16x8 kpre[4], vpre[4];

    {
        const size_t growK = (size_t)(b * Pn + 0 + tokK) * Cn;
        #pragma unroll
        for (int i = 0; i < 4; i++)
            kpre[i] = *(const u16x8*)&Kg[growK + (size_t)(8 * i + (giK ^ (tokK & 7))) * 8];
        #pragma unroll
        for (int i = 0; i < 4; i++) {
            int cl = cbV + 64 * i;
            vpre[i] = *(const u16x8*)&Vt[((size_t)(b * Cn + cl)) * Pn + 0 + gvV * 8];
        }
    }

    for (int kt = 0; kt < 32; kt++) {
        __syncthreads();   // (A) all waves done reading LDS of prev iter

        #pragma unroll
        for (int i = 0; i < 4; i++)
            *(u16x8*)&Klds[tokK * 256 + (8 * i + giK) * 8] = kpre[i];
        #pragma unroll
        for (int i = 0; i < 4; i++) {
            int cl = cbV + 64 * i;
            int gp = gvV ^ (cl & 3);
            *(u16x8*)&Vtlds[cl * 32 + gp * 8] = vpre[i];
        }
        __syncthreads();   // (B) tile visible

        if (kt < 31) {
            const int k0n = (kt + 1) * 32;
            const size_t growK = (size_t)(b * Pn + k0n + tokK) * Cn;
            #pragma unroll
            for (int i = 0; i < 4; i++)
                kpre[i] = *(const u16x8*)&Kg[growK + (size_t)(8 * i + (giK ^ (tokK & 7))) * 8];
            #pragma unroll
            for (int i = 0; i < 4; i++) {
                int cl = cbV + 64 * i;
                vpre[i] = *(const u16x8*)&Vt[((size_t)(b * Cn + cl)) * Pn + k0n + gvV * 8];
            }
        }

        // --- QK^T swapped: S^T = mfma(K, Q). Lane: q = ln, k = st*16+quad*4+r.
        u32 pk1[4], pk2[4];
        #pragma unroll
        for (int st = 0; st < 2; st++) {
            f32x4 s1 = (f32x4){0.f, 0.f, 0.f, 0.f};
            f32x4 s2 = (f32x4){0.f, 0.f, 0.f, 0.f};
            #pragma unroll
            for (int ch = 0; ch < 8; ch++) {
                bf16x8 kb = *(const bf16x8*)
                    &Klds[(st * 16 + ln) * 256 + (((ch * 4 + quad) ^ (ln & 7))) * 8];
                s1 = __builtin_amdgcn_mfma_f32_16x16x32_bf16(kb, qa1[ch], s1, 0, 0, 0);
                s2 = __builtin_amdgcn_mfma_f32_16x16x32_bf16(kb, qa2[ch], s2, 0, 0, 0);
            }
            float p1v[4], p2v[4];
            #pragma unroll
            for (int r = 0; r < 4; r++) {
                float e1 = __expf(s1[r]);
                float e12 = e1 * __expf(s2[r]);
                lp1 += e1;
                lp12 += e12;
                p1v[r] = e1;
                p2v[r] = e12;
            }
            pk1[st * 2 + 0] = cvt_pk_bf16(p1v[0], p1v[1]);
            pk1[st * 2 + 1] = cvt_pk_bf16(p1v[2], p1v[3]);
            pk2[st * 2 + 0] = cvt_pk_bf16(p2v[0], p2v[1]);
            pk2[st * 2 + 1] = cvt_pk_bf16(p2v[2], p2v[3]);
        }

        // in-register transpose to PV B-fragment layout (q=ln, k=quad*8..+8)
        pl32swap(pk1[0], pk1[2]); pl32swap(pk1[1], pk1[3]);
        pl32swap(pk2[0], pk2[2]); pl32swap(pk2[1], pk2[3]);
        pl16swap(pk1[0], pk1[2]); pl16swap(pk1[1], pk1[3]);
        pl16swap(pk2[0], pk2[2]); pl16swap(pk2[1], pk2[3]);

        bf16x8 pa1 = pkfrag(pk1[0], pk1[1], pk1[2], pk1[3]);
        bf16x8 pa2 = pkfrag(pk2[0], pk2[1], pk2[2], pk2[3]);

        // --- PV: O^T = mfma(V^T, P^T). acc[t] holds c = t*16+quad*4+r, q = ln.
        #pragma unroll
        for (int t = 0; t < 16; t++) {
            bf16x8 vb = *(const bf16x8*)
                &Vtlds[(t * 16 + ln) * 32 + (quad ^ (ln & 3)) * 8];
            acc1[t]  = __builtin_amdgcn_mfma_f32_16x16x32_bf16(vb, pa1, acc1[t], 0, 0, 0);
            acc12[t] = __builtin_amdgcn_mfma_f32_16x16x32_bf16(vb, pa2, acc12[t], 0, 0, 0);
        }
    }

    // row-sum reduction: lanes ln, ln+16, ln+32, ln+48 hold disjoint k-classes
    lp1  += __shfl_xor(lp1, 16);  lp1  += __shfl_xor(lp1, 32);
    lp12 += __shfl_xor(lp12, 16); lp12 += __shfl_xor(lp12, 32);
    const float i1 = 1.f / lp1, i2 = 1.f / lp12;

    u16* H1 = ws16 + H1o;
    u16* H12 = ws16 + H12o;
    const size_t rowb = (size_t)(b * Pn + q0 + wid * 16 + ln) * Cn;
    #pragma unroll
    for (int t = 0; t < 16; t++) {
        ushort4 o1, o2;
        o1.x = f2b(acc1[t][0] * i1);  o1.y = f2b(acc1[t][1] * i1);
        o1.z = f2b(acc1[t][2] * i1);  o1.w = f2b(acc1[t][3] * i1);
        o2.x = f2b(acc12[t][0] * i2); o2.y = f2b(acc12[t][1] * i2);
        o2.z = f2b(acc12[t][2] * i2); o2.w = f2b(acc12[t][3] * i2);
        *(ushort4*)&H1[rowb + t * 16 + quad * 4]  = o1;
        *(ushort4*)&H12[rowb + t * 16 + quad * 4] = o2;
    }
}

// ---------------------------------------------------------------------------
// outproj: out[mat][b][o][p] = x1[b][o][p] + bias[o] + sum_c h[b][p][c]*w[o][c]
// grid (16, 64); block 256
// ---------------------------------------------------------------------------
__global__ __launch_bounds__(256) void outproj_kernel(
    const float* __restrict__ x1,
    const float* __restrict__ bps, const float* __restrict__ bpc,
    const u16* __restrict__ ws16, float* __restrict__ outp)
{
    __shared__ __align__(16) u16 As[128 * 64];
    __shared__ __align__(16) u16 Bs[128 * 64];
    const int tid = threadIdx.x;
    const int o_tile = blockIdx.x >> 3, p_tile = blockIdx.x & 7;
    const int mat = blockIdx.y >> 5, b = blockIdx.y & 31;
    const int wv = tid >> 6, lane = tid & 63;
    const int ln = lane & 15, quad = lane >> 4;
    const int wr = wv >> 1, wc = wv & 1;

    f32x4 acc[16];
    #pragma unroll
    for (int t = 0; t < 16; t++) acc[t] = (f32x4){0.f, 0.f, 0.f, 0.f};

    const u16* Ab = ws16 + WBo + (size_t)(4 + mat) * 65536 + (size_t)o_tile * 128 * 256;
    const u16* Bb = ws16 + (mat ? H12o : H1o) + ((size_t)b * Pn + p_tile * 128) * 256;
    gemm_core(Ab, Bb, As, Bs, acc, tid);

    const float* bias = mat ? bpc : bps;
    float* out = outp + (size_t)mat * Tn;
    #pragma unroll
    for (int i = 0; i < 4; i++) {
        #pragma unroll
        for (int r = 0; r < 4; r++) {
            const int orow = o_tile * 128 + wr * 64 + i * 16 + quad * 4 + r;
            const float bo = bias[orow];
            #pragma unroll
            for (int j = 0; j < 4; j++) {
                const int pcol = p_tile * 128 + wc * 64 + j * 16 + ln;
                const size_t idx = ((size_t)b * Cn + orow) * Pn + pcol;
                out[idx] = x1[idx] + bo + acc[i * 4 + j][r];
            }
        }
    }
}

// ---------------------------------------------------------------------------
extern "C" void kernel_launch(void* const* d_in, const int* in_sizes, int n_in,
                              void* d_out, int out_size, void* d_ws, size_t ws_size,
                              hipStream_t stream)
{
    const float* x1  = (const float*)d_in[0];
    const float* x2  = (const float*)d_in[1];
    const float* wq1 = (const float*)d_in[2];
    const float* bq1 = (const float*)d_in[3];
    const float* wk  = (const float*)d_in[4];
    const float* bk  = (const float*)d_in[5];
    const float* wv  = (const float*)d_in[6];
    const float* bv  = (const float*)d_in[7];
    const float* wq2 = (const float*)d_in[8];
    const float* bq2 = (const float*)d_in[9];
    const float* wps = (const float*)d_in[10];
    const float* bps = (const float*)d_in[11];
    const float* wpc = (const float*)d_in[12];
    const float* bpc = (const float*)d_in[13];
    float* out = (float*)d_out;
    u16* ws16 = (u16*)d_ws;

    cvt_kernel<<<dim3(16, 4, 70), 256, 0, stream>>>(
        x1, x2, wq1, wk, wv, wq2, wps, wpc, ws16);
    proj_kernel<<<dim3(512, 4), 256, 0, stream>>>(ws16, bq1, bk, bq2, bv);
    attn_kernel<<<dim3(Pn / 64, Bn), 256, 0, stream>>>(ws16);
    outproj_kernel<<<dim3(16, 64), 256, 0, stream>>>(x1, bps, bpc, ws16, out);
}

// Round 3
// 345.332 us; speedup vs baseline: 1.6038x; 1.0362x over previous
//
#include <hip/hip_runtime.h>
#include <math.h>

#define Bn 32
#define Cn 256
#define Pn 1024                       // H*W tokens per batch
#define Tn (Bn * Pn * Cn)             // 8,388,608 elems per [b,p,c] tensor

typedef __bf16 bf16x8 __attribute__((ext_vector_type(8)));
typedef float  f32x4  __attribute__((ext_vector_type(4)));
typedef unsigned short u16;
typedef u16 u16x8 __attribute__((ext_vector_type(8)));

// ws layout in u16 units (total ~129 MiB):
#define XT1o ((size_t)0)              // xt of x1: [b][p][c] bf16
#define XT2o ((size_t)1 * Tn)         // xt of x2
#define Q1o  ((size_t)2 * Tn)         // q1 bf16 [b][p][c], pre-scaled 1/16
#define Ko   ((size_t)3 * Tn)         // k  bf16 [b][p][c]
#define VTo  ((size_t)4 * Tn)         // vt bf16 [b][c][p]
#define Q2o  ((size_t)5 * Tn)         // q2 bf16 [b][p][c], pre-scaled 1/16
#define H1o  ((size_t)6 * Tn)         // h1 bf16 [b][p][c]
#define H12o ((size_t)7 * Tn)         // h12 bf16 [b][p][c]
#define WBo  ((size_t)8 * Tn)         // 6 weight mats bf16 [o][c]: q1,k,v,q2,ps,pc

__device__ __forceinline__ u16 f2b(float f) {
    union { float f; unsigned u; } c; c.f = f;
    return (u16)((c.u + 0x7FFFu + ((c.u >> 16) & 1u)) >> 16);
}

// ---------------------------------------------------------------------------
// cvt: x1,x2 [b][c][p] fp32 -> xt [b][p][c] bf16 ; weights fp32 -> bf16.
// grid (16, 4, 70); block 256.
// ---------------------------------------------------------------------------
__global__ __launch_bounds__(256) void cvt_kernel(
    const float* __restrict__ x1, const float* __restrict__ x2,
    const float* __restrict__ wq1, const float* __restrict__ wk,
    const float* __restrict__ wv,  const float* __restrict__ wq2,
    const float* __restrict__ wps, const float* __restrict__ wpc,
    u16* __restrict__ ws16)
{
    const int z = blockIdx.z;
    const int tid = threadIdx.x;
    if (z >= 64) {
        const int widx = z - 64;
        const float* w = widx == 0 ? wq1 : widx == 1 ? wk : widx == 2 ? wv
                       : widx == 3 ? wq2 : widx == 4 ? wps : wpc;
        const int linear = blockIdx.x + 16 * blockIdx.y;   // 0..63
        const int e = linear * 1024 + tid * 4;
        float4 v = *(const float4*)&w[e];
        ushort4 o = make_ushort4(f2b(v.x), f2b(v.y), f2b(v.z), f2b(v.w));
        *(ushort4*)&ws16[WBo + (size_t)widx * 65536 + e] = o;
        return;
    }
    const int which = z >> 5, b = z & 31;
    const float* x = which ? x2 : x1;
    u16* xt = ws16 + (which ? XT2o : XT1o);
    const int p0 = blockIdx.x * 64, c0 = blockIdx.y * 64;
    __shared__ __align__(16) u16 T[64][80];
    #pragma unroll
    for (int i = 0; i < 4; i++) {
        int e = tid + i * 256;
        int c = e >> 4, p4 = e & 15;
        float4 v = *(const float4*)&x[((size_t)(b * Cn + c0 + c)) * Pn + p0 + p4 * 4];
        T[p4 * 4 + 0][c] = f2b(v.x);
        T[p4 * 4 + 1][c] = f2b(v.y);
        T[p4 * 4 + 2][c] = f2b(v.z);
        T[p4 * 4 + 3][c] = f2b(v.w);
    }
    __syncthreads();
    #pragma unroll
    for (int i = 0; i < 2; i++) {
        int e = tid + i * 256;
        int p = e >> 3, c8 = e & 7;
        u16x8 vv = *(const u16x8*)&T[p][c8 * 8];
        *(u16x8*)&xt[((size_t)(b * Pn + p0 + p)) * Cn + c0 + c8 * 8] = vv;
    }
}

// ---------------------------------------------------------------------------
// Shared 128x128x256 MFMA GEMM core, register-prefetch pipeline (R5 lesson).
// ---------------------------------------------------------------------------
__device__ __forceinline__ void gemm_core(
    const u16* __restrict__ Ab, const u16* __restrict__ Bb,
    u16* __restrict__ As, u16* __restrict__ Bs, f32x4 acc[16], int tid)
{
    const int wv = tid >> 6, lane = tid & 63;
    const int ln = lane & 15, quad = lane >> 4;
    const int wr = wv >> 1, wc = wv & 1;
    const int srow = tid >> 3, sch = tid & 7;    // staging role
    const int pos = sch ^ (srow & 7);            // (srow+32i)&7 == srow&7

    u16x8 apre[4], bpre[4];
    #pragma unroll
    for (int i = 0; i < 4; i++) {
        int r = srow + 32 * i;
        apre[i] = *(const u16x8*)&Ab[(size_t)r * 256 + sch * 8];
        bpre[i] = *(const u16x8*)&Bb[(size_t)r * 256 + sch * 8];
    }

    for (int k0 = 0; k0 < 256; k0 += 64) {
        __syncthreads();
        #pragma unroll
        for (int i = 0; i < 4; i++) {
            int r = srow + 32 * i;
            *(u16x8*)&As[r * 64 + pos * 8] = apre[i];
            *(u16x8*)&Bs[r * 64 + pos * 8] = bpre[i];
        }
        __syncthreads();
        if (k0 < 192) {
            #pragma unroll
            for (int i = 0; i < 4; i++) {
                int r = srow + 32 * i;
                apre[i] = *(const u16x8*)&Ab[(size_t)r * 256 + (k0 + 64) + sch * 8];
                bpre[i] = *(const u16x8*)&Bb[(size_t)r * 256 + (k0 + 64) + sch * 8];
            }
        }
        bf16x8 af[4][2], bf[4][2];
        #pragma unroll
        for (int i = 0; i < 4; i++) {
            int row = wr * 64 + i * 16 + ln;
            #pragma unroll
            for (int kc = 0; kc < 2; kc++) {
                int p = (kc * 4 + quad) ^ (row & 7);
                af[i][kc] = *(const bf16x8*)&As[row * 64 + p * 8];
            }
        }
        #pragma unroll
        for (int j = 0; j < 4; j++) {
            int row = wc * 64 + j * 16 + ln;
            #pragma unroll
            for (int kc = 0; kc < 2; kc++) {
                int p = (kc * 4 + quad) ^ (row & 7);
                bf[j][kc] = *(const bf16x8*)&Bs[row * 64 + p * 8];
            }
        }
        #pragma unroll
        for (int kc = 0; kc < 2; kc++)
            #pragma unroll
            for (int i = 0; i < 4; i++)
                #pragma unroll
                for (int j = 0; j < 4; j++)
                    acc[i * 4 + j] = __builtin_amdgcn_mfma_f32_16x16x32_bf16(
                        af[i][kc], bf[j][kc], acc[i * 4 + j], 0, 0, 0);
    }
}

// ---------------------------------------------------------------------------
// proj: q1/k/q2 (mat 0,1,2): [32768 x 256] = xt . W^T ; V (mat 3): vt = W . xt^T
// grid (512, 4); block 256
// ---------------------------------------------------------------------------
__global__ __launch_bounds__(256) void proj_kernel(
    u16* __restrict__ ws16,
    const float* __restrict__ bq1, const float* __restrict__ bk,
    const float* __restrict__ bq2, const float* __restrict__ bv)
{
    __shared__ __align__(16) u16 As[128 * 64];
    __shared__ __align__(16) u16 Bs[128 * 64];
    const int tid = threadIdx.x;
    const int mat = blockIdx.y;
    const int wv = tid >> 6, lane = tid & 63;
    const int ln = lane & 15, quad = lane >> 4;
    const int wr = wv >> 1, wc = wv & 1;

    f32x4 acc[16];
    #pragma unroll
    for (int t = 0; t < 16; t++) acc[t] = (f32x4){0.f, 0.f, 0.f, 0.f};

    if (mat < 3) {
        const int m_tile = blockIdx.x >> 1, n_tile = blockIdx.x & 1;
        const size_t xtoff = (mat == 2) ? XT2o : XT1o;
        const int widx = (mat == 0) ? 0 : (mat == 1) ? 1 : 3;
        const float* bias = (mat == 0) ? bq1 : (mat == 1) ? bk : bq2;
        const float scale = (mat == 1) ? 1.0f : 0.0625f;
        u16* out = ws16 + ((mat == 0) ? Q1o : (mat == 1) ? Ko : Q2o);

        const u16* Ab = ws16 + xtoff + (size_t)m_tile * 128 * 256;
        const u16* Bb = ws16 + WBo + (size_t)widx * 65536 + (size_t)n_tile * 128 * 256;
        gemm_core(Ab, Bb, As, Bs, acc, tid);

        const int m0 = m_tile * 128;
        #pragma unroll
        for (int j = 0; j < 4; j++) {
            const int ncol = n_tile * 128 + wc * 64 + j * 16 + ln;
            const float bj = bias[ncol];
            #pragma unroll
            for (int i = 0; i < 4; i++) {
                const int mr = m0 + wr * 64 + i * 16 + quad * 4;
                #pragma unroll
                for (int r = 0; r < 4; r++)
                    out[(size_t)(mr + r) * 256 + ncol] =
                        f2b((acc[i * 4 + j][r] + bj) * scale);
            }
        }
    } else {
        const int b = blockIdx.x >> 4;
        const int o_tile = (blockIdx.x >> 3) & 1;
        const int p_tile = blockIdx.x & 7;
        const u16* Ab = ws16 + WBo + (size_t)2 * 65536 + (size_t)o_tile * 128 * 256;
        const u16* Bb = ws16 + XT1o + ((size_t)b * Pn + p_tile * 128) * 256;
        gemm_core(Ab, Bb, As, Bs, acc, tid);

        u16* vt = ws16 + VTo + (size_t)b * Cn * Pn;
        #pragma unroll
        for (int i = 0; i < 4; i++) {
            #pragma unroll
            for (int r = 0; r < 4; r++) {
                const int orow = o_tile * 128 + wr * 64 + i * 16 + quad * 4 + r;
                const float bo = bv[orow];
                #pragma unroll
                for (int j = 0; j < 4; j++) {
                    const int pcol = p_tile * 128 + wc * 64 + j * 16 + ln;
                    vt[(size_t)orow * Pn + pcol] = f2b(acc[i * 4 + j][r] + bo);
                }
            }
        }
    }
}

// ---------------------------------------------------------------------------
// attn v6: exact v3 loop body (verified 105 us) + two isolated additions:
//  (1) XCD-affinity remap: XCD x serves only batches 4x..4x+3, so each XCD's
//      K+V working set is 4 MB = its L2 (was: all 32 batches = 64 MB/XCD,
//      near-zero L2 reuse, FETCH=150MB vs ideal 64MB).
//  (2) s_setprio(1) around the QK and PV MFMA clusters (T5; attn +4-7% per
//      guide m191; 2 blocks/CU give the scheduler cross-block role diversity).
// v5 lesson: the P-LDS path was NOT the conflict source (8.9M -> 8.4M after
// removing it entirely); K/V b128 ops are at the structural 8-cycle minimum
// and the counter counts that. v3 is latency-bound, not LDS-bound.
// block = 4 waves = 64 q-rows; 32 k-tokens per iter. grid (16, 32).
// ---------------------------------------------------------------------------
__global__ __launch_bounds__(256, 2) void attn_kernel(u16* __restrict__ ws16)
{
    const u16* Q1 = ws16 + Q1o;
    const u16* Kg = ws16 + Ko;
    const u16* Vt = ws16 + VTo;
    const u16* Q2 = ws16 + Q2o;

    __shared__ __align__(16) u16 Klds[32 * 256];    // [tok][c], chunk swizzle ^ (tok&7)
    __shared__ __align__(16) u16 Vtlds[256 * 32];   // [c][tok], chunk swizzle ^ (c&3)
    __shared__ __align__(16) u16 Plds[4 * 2 * 16 * 40];  // per-wave P1/P12, pad 40

    // XCD-affinity remap (bijective over 512 blocks):
    // fid bits [2:0] -> b[4:2] (= XCD id, since linear wg id round-robins),
    // fid bits [4:3] -> b[1:0], fid bits [8:5] -> q-tile.
    const int fid = blockIdx.x + (blockIdx.y << 4);
    const int b   = ((fid & 7) << 2) | ((fid >> 3) & 3);
    const int q0  = (fid >> 5) << 6;

    const int tid  = threadIdx.x;
    const int wid  = tid >> 6;
    const int lane = tid & 63;
    const int ln   = lane & 15;
    const int quad = lane >> 4;
    u16* Pw = Plds + wid * (2 * 16 * 40);

    const size_t qrow = (size_t)(b * Pn + q0 + wid * 16 + ln) * Cn;
    bf16x8 qa1[8], qa2[8];
    #pragma unroll
    for (int ch = 0; ch < 8; ch++) {
        qa1[ch] = *(const bf16x8*)&Q1[qrow + ch * 32 + quad * 8];
        qa2[ch] = *(const bf16x8*)&Q2[qrow + ch * 32 + quad * 8];
    }

    f32x4 acc1[16], acc12[16];
    #pragma unroll
    for (int t = 0; t < 16; t++) {
        acc1[t] = (f32x4){0.f, 0.f, 0.f, 0.f};
        acc12[t] = (f32x4){0.f, 0.f, 0.f, 0.f};
    }
    float lp1[4] = {}, lp12[4] = {};

    const int tokK = tid >> 3, giK = tid & 7;
    const int cbV = tid >> 2, gvV = tid & 3;
    u16x8 kpre[4], vpre[4];

    {
        const size_t growK = (size_t)(b * Pn + 0 + tokK) * Cn;
        #pragma unroll
        for (int i = 0; i < 4; i++)
            kpre[i] = *(const u16x8*)&Kg[growK + (size_t)(8 * i + (giK ^ (tokK & 7))) * 8];
        #pragma unroll
        for (int i = 0; i < 4; i++) {
            int cl = cbV + 64 * i;
            vpre[i] = *(const u16x8*)&Vt[((size_t)(b * Cn + cl)) * Pn + 0 + gvV * 8];
        }
    }

    for (int kt = 0; kt < 32; kt++) {
        __syncthreads();   // (A) all waves done reading LDS of prev iter

        #pragma unroll
        for (int i = 0; i < 4; i++)
            *(u16x8*)&Klds[tokK * 256 + (8 * i + giK) * 8] = kpre[i];
        #pragma unroll
        for (int i = 0; i < 4; i++) {
            int cl = cbV + 64 * i;
            int gp = gvV ^ (cl & 3);
            *(u16x8*)&Vtlds[cl * 32 + gp * 8] = vpre[i];
        }
        __syncthreads();   // (B) tile visible

        if (kt < 31) {
            const int k0n = (kt + 1) * 32;
            const size_t growK = (size_t)(b * Pn + k0n + tokK) * Cn;
            #pragma unroll
            for (int i = 0; i < 4; i++)
                kpre[i] = *(const u16x8*)&Kg[growK + (size_t)(8 * i + (giK ^ (tokK & 7))) * 8];
            #pragma unroll
            for (int i = 0; i < 4; i++) {
                int cl = cbV + 64 * i;
                vpre[i] = *(const u16x8*)&Vt[((size_t)(b * Cn + cl)) * Pn + k0n + gvV * 8];
            }
        }

        float s1v[2][4], s2v[2][4];
        #pragma unroll
        for (int st = 0; st < 2; st++) {
            f32x4 s1 = (f32x4){0.f, 0.f, 0.f, 0.f};
            f32x4 s2 = (f32x4){0.f, 0.f, 0.f, 0.f};
            __builtin_amdgcn_s_setprio(1);
            #pragma unroll
            for (int ch = 0; ch < 8; ch++) {
                bf16x8 kb = *(const bf16x8*)
                    &Klds[(st * 16 + ln) * 256 + (((ch * 4 + quad) ^ (ln & 7))) * 8];
                s1 = __builtin_amdgcn_mfma_f32_16x16x32_bf16(qa1[ch], kb, s1, 0, 0, 0);
                s2 = __builtin_amdgcn_mfma_f32_16x16x32_bf16(qa2[ch], kb, s2, 0, 0, 0);
            }
            __builtin_amdgcn_s_setprio(0);
            #pragma unroll
            for (int r = 0; r < 4; r++) { s1v[st][r] = s1[r]; s2v[st][r] = s2[r]; }
        }

        #pragma unroll
        for (int st = 0; st < 2; st++)
            #pragma unroll
            for (int r = 0; r < 4; r++) {
                float p1 = __expf(s1v[st][r]);
                float p12 = p1 * __expf(s2v[st][r]);
                lp1[r] += p1;
                lp12[r] += p12;
                int row = quad * 4 + r, col = st * 16 + ln;
                Pw[row * 40 + col]            = f2b(p1);
                Pw[16 * 40 + row * 40 + col]  = f2b(p12);
            }

        bf16x8 pa1 = *(const bf16x8*)&Pw[ln * 40 + quad * 8];
        bf16x8 pa2 = *(const bf16x8*)&Pw[16 * 40 + ln * 40 + quad * 8];
        __builtin_amdgcn_s_setprio(1);
        #pragma unroll
        for (int t = 0; t < 16; t++) {
            bf16x8 vb = *(const bf16x8*)
                &Vtlds[(t * 16 + ln) * 32 + (quad ^ (ln & 3)) * 8];
            acc1[t]  = __builtin_amdgcn_mfma_f32_16x16x32_bf16(pa1, vb, acc1[t], 0, 0, 0);
            acc12[t] = __builtin_amdgcn_mfma_f32_16x16x32_bf16(pa2, vb, acc12[t], 0, 0, 0);
        }
        __builtin_amdgcn_s_setprio(0);
    }

    u16* H1 = ws16 + H1o;
    u16* H12 = ws16 + H12o;
    #pragma unroll
    for (int r = 0; r < 4; r++) {
        float l1 = lp1[r], l2 = lp12[r];
        l1 += __shfl_xor(l1, 1); l2 += __shfl_xor(l2, 1);
        l1 += __shfl_xor(l1, 2); l2 += __shfl_xor(l2, 2);
        l1 += __shfl_xor(l1, 4); l2 += __shfl_xor(l2, 4);
        l1 += __shfl_xor(l1, 8); l2 += __shfl_xor(l2, 8);
        float i1 = 1.f / l1, i2 = 1.f / l2;
        size_t rowb = (size_t)(b * Pn + q0 + wid * 16 + quad * 4 + r) * Cn;
        #pragma unroll
        for (int t = 0; t < 16; t++) {
            H1[rowb + t * 16 + ln]  = f2b(acc1[t][r] * i1);
            H12[rowb + t * 16 + ln] = f2b(acc12[t][r] * i2);
        }
    }
}

// ---------------------------------------------------------------------------
// outproj: out[mat][b][o][p] = x1[b][o][p] + bias[o] + sum_c h[b][p][c]*w[o][c]
// grid (16, 64); block 256
// ---------------------------------------------------------------------------
__global__ __launch_bounds__(256) void outproj_kernel(
    const float* __restrict__ x1,
    const float* __restrict__ bps, const float* __restrict__ bpc,
    const u16* __restrict__ ws16, float* __restrict__ outp)
{
    __shared__ __align__(16) u16 As[128 * 64];
    __shared__ __align__(16) u16 Bs[128 * 64];
    const int tid = threadIdx.x;
    const int o_tile = blockIdx.x >> 3, p_tile = blockIdx.x & 7;
    const int mat = blockIdx.y >> 5, b = blockIdx.y & 31;
    const int wv = tid >> 6, lane = tid & 63;
    const int ln = lane & 15, quad = lane >> 4;
    const int wr = wv >> 1, wc = wv & 1;

    f32x4 acc[16];
    #pragma unroll
    for (int t = 0; t < 16; t++) acc[t] = (f32x4){0.f, 0.f, 0.f, 0.f};

    const u16* Ab = ws16 + WBo + (size_t)(4 + mat) * 65536 + (size_t)o_tile * 128 * 256;
    const u16* Bb = ws16 + (mat ? H12o : H1o) + ((size_t)b * Pn + p_tile * 128) * 256;
    gemm_core(Ab, Bb, As, Bs, acc, tid);

    const float* bias = mat ? bpc : bps;
    float* out = outp + (size_t)mat * Tn;
    #pragma unroll
    for (int i = 0; i < 4; i++) {
        #pragma unroll
        for (int r = 0; r < 4; r++) {
            const int orow = o_tile * 128 + wr * 64 + i * 16 + quad * 4 + r;
            const float bo = bias[orow];
            #pragma unroll
            for (int j = 0; j < 4; j++) {
                const int pcol = p_tile * 128 + wc * 64 + j * 16 + ln;
                const size_t idx = ((size_t)b * Cn + orow) * Pn + pcol;
                out[idx] = x1[idx] + bo + acc[i * 4 + j][r];
            }
        }
    }
}

// ---------------------------------------------------------------------------
extern "C" void kernel_launch(void* const* d_in, const int* in_sizes, int n_in,
                              void* d_out, int out_size, void* d_ws, size_t ws_size,
                              hipStream_t stream)
{
    const float* x1  = (const float*)d_in[0];
    const float* x2  = (const float*)d_in[1];
    const float* wq1 = (const float*)d_in[2];
    const float* bq1 = (const float*)d_in[3];
    const float* wk  = (const float*)d_in[4];
    const float* bk  = (const float*)d_in[5];
    const float* wv  = (const float*)d_in[6];
    const float* bv  = (const float*)d_in[7];
    const float* wq2 = (const float*)d_in[8];
    const float* bq2 = (const float*)d_in[9];
    const float* wps = (const float*)d_in[10];
    const float* bps = (const float*)d_in[11];
    const float* wpc = (const float*)d_in[12];
    const float* bpc = (const float*)d_in[13];
    float* out = (float*)d_out;
    u16* ws16 = (u16*)d_ws;

    cvt_kernel<<<dim3(16, 4, 70), 256, 0, stream>>>(
        x1, x2, wq1, wk, wv, wq2, wps, wpc, ws16);
    proj_kernel<<<dim3(512, 4), 256, 0, stream>>>(ws16, bq1, bk, bq2, bv);
    attn_kernel<<<dim3(Pn / 64, Bn), 256, 0, stream>>>(ws16);
    outproj_kernel<<<dim3(16, 64), 256, 0, stream>>>(x1, bps, bpc, ws16, out);
}